// Round 7
// baseline (246.315 us; speedup 1.0000x reference)
//
#include <hip/hip_runtime.h>

// Inputs (setup_inputs order):
//   d_in[0] image_batch  [tf, 1024] f32
//   d_in[1] emo_batch    [tf, 1024] f32   (UNUSED by reference)
//   d_in[2] clip_batch   [tc, 1024] f32
//   d_in[3] num_frames_batch [B] i32
//   d_in[4] num_clips_batch  [B] i32
//   d_in[5] pad_idx (scalar i32)
// Output: x [B, L, 2048] f32 flat, then src_length [B] stored as FLOAT values.
//
// R3/R5 profiling: harness re-poison fills (2 x ~93us at 6.7 TB/s, 623 MB)
// are a ~186us floor inside dur_us. Gather itself ~52us vs ~34us BW ideal.
// R6: CH=4 rows per block -> clip row read once per block (L1-reuses the
// other 3), 4x fewer prologues, deeper MLP via full unroll.

#define D_IMG 1024
#define D_TOT 2048
#define CH 4   // rows (j positions) per block; matches rf=4 clip reuse span

typedef float f32x4 __attribute__((ext_vector_type(4)));

__global__ void __launch_bounds__(256)
gather_kernel(const float* __restrict__ image,
              const float* __restrict__ clip,
              const int* __restrict__ nf,
              const int* __restrict__ nc,
              const int* __restrict__ pad_idx_p,
              float* __restrict__ out,
              float* __restrict__ src_len,
              int L, int B) {
    const int jb = blockIdx.x;     // row-group: rows [jb*CH, jb*CH+CH)
    const int b  = blockIdx.y;     // batch index
    const int t  = threadIdx.x;    // 0..255
    const int lane = t & 63;

    // Wave-parallel exclusive prefix sums over nf/nc (B<=64).
    int nfv = 0, ncv = 0;
    if (lane < B) { nfv = nf[lane]; ncv = nc[lane]; }
    const int nf_b = __shfl(nfv, b);
    const int nc_b = __shfl(ncv, b);
    int fo = (lane < b) ? nfv : 0;
    int co = (lane < b) ? ncv : 0;
    #pragma unroll
    for (int off = 32; off > 0; off >>= 1) {
        fo += __shfl_xor(fo, off);
        co += __shfl_xor(co, off);
    }
    // fo = foff[b], co = coff[b], wave-uniform.

    if (jb == 0 && t == 0) src_len[b] = (float)nf_b;  // harness reads f32

    const int j0 = jb * CH;
    const int rf = nf_b / nc_b;
    const int last = nc_b - 1;

    // Pad value only needed if this block touches rows >= nf_b.
    f32x4 p4 = {0.f, 0.f, 0.f, 0.f};
    if (j0 + CH > nf_b) {
        const float pv = (float)(*pad_idx_p);
        p4 = (f32x4){pv, pv, pv, pv};
    }

    #pragma unroll
    for (int r = 0; r < CH; ++r) {
        const int j = j0 + r;
        if (j >= L) continue;
        f32x4* out4 = (f32x4*)(out + (size_t)(b * L + j) * D_TOT);
        if (j >= nf_b) {
            __builtin_nontemporal_store(p4, &out4[t]);
            __builtin_nontemporal_store(p4, &out4[256 + t]);
        } else {
            int cidx = j / rf;
            if (cidx > last) cidx = last;
            const f32x4* img4 = (const f32x4*)(image + (size_t)(fo + j) * D_IMG);
            const f32x4* clp4 = (const f32x4*)(clip  + (size_t)(co + cidx) * D_IMG);
            // image: read-once -> NT load; clip: reused within block -> cached (L1).
            f32x4 iv = __builtin_nontemporal_load(&img4[t]);
            f32x4 cv = clp4[t];
            __builtin_nontemporal_store(iv, &out4[t]);        // [0,1024)
            __builtin_nontemporal_store(cv, &out4[256 + t]);  // [1024,2048)
        }
    }
}

extern "C" void kernel_launch(void* const* d_in, const int* in_sizes, int n_in,
                              void* d_out, int out_size, void* d_ws, size_t ws_size,
                              hipStream_t stream) {
    const float* image = (const float*)d_in[0];
    // d_in[1] (emo_batch) is unused by the reference.
    const float* clip  = (const float*)d_in[2];
    const int*   nf    = (const int*)d_in[3];
    const int*   nc    = (const int*)d_in[4];
    const int*   pad   = (const int*)d_in[5];

    const int B = in_sizes[3];
    const int L = (out_size - B) / (B * D_TOT);

    float* out = (float*)d_out;
    float* src_len = (float*)d_out + (size_t)B * L * D_TOT;  // tail: src_length [B]

    dim3 grid((L + CH - 1) / CH, B);
    gather_kernel<<<grid, 256, 0, stream>>>(image, clip, nf, nc, pad, out, src_len, L, B);
}

// Round 11
// 242.555 us; speedup vs baseline: 1.0155x; 1.0155x over previous
//
#include <hip/hip_runtime.h>

// Inputs (setup_inputs order):
//   d_in[0] image_batch  [tf, 1024] f32
//   d_in[1] emo_batch    [tf, 1024] f32   (UNUSED by reference)
//   d_in[2] clip_batch   [tc, 1024] f32
//   d_in[3] num_frames_batch [B] i32
//   d_in[4] num_clips_batch  [B] i32
//   d_in[5] pad_idx (scalar i32)
// Output: x [B, L, 2048] f32 flat, then src_length [B] stored as FLOAT values.
//
// Journal: R3/R5 profiling: harness re-poison fills (2 x ~93us at 6.7 TB/s,
// 623 MB each) are a ~186us floor inside dur_us. R5 (1 row/block, NT hints,
// shuffle prefix) = 238.2us total -> gather ~52us vs ~34us BW ideal.
// R7 (CH=4 rows/block) = 246.3us: intra-block serialization REGRESSED; revert.
// R8-R10: R5 structure + flat 1D grid + chunked XCD swizzle (T1): the 4
// consecutive-j blocks sharing a clip row land on the SAME XCD's L2,
// cutting ~41MB of cross-XCD clip re-fetch, without serializing rows.
// (R8/R9/R10 resubmissions -- broker at capacity, never ran.)

#define D_IMG 1024
#define D_TOT 2048
#define NXCD 8

typedef float f32x4 __attribute__((ext_vector_type(4)));

// One 256-thread block per output row (b, j). Each thread moves 2 f32x4.
__global__ void __launch_bounds__(256)
gather_kernel(const float* __restrict__ image,
              const float* __restrict__ clip,
              const int* __restrict__ nf,
              const int* __restrict__ nc,
              const int* __restrict__ pad_idx_p,
              float* __restrict__ out,
              float* __restrict__ src_len,
              int L, int B, int chunk) {
    // XCD-aware swizzle: hardware assigns original id oid to XCD oid%8.
    // wid = (oid%8)*chunk + oid/8 gives each XCD a contiguous wid range,
    // so adjacent-j rows (sharing a clip row) stay in one XCD's L2.
    // chunk = nwg/8 (nwg = B*L, divisible by 8 since B=32); chunk==0 -> identity.
    const int oid = blockIdx.x;
    const int wid = chunk ? (oid & (NXCD - 1)) * chunk + (oid >> 3) : oid;
    const int b = wid / L;
    const int j = wid - b * L;
    const int t = threadIdx.x;     // 0..255
    const int lane = t & 63;

    // Wave-parallel exclusive prefix sums: lane i holds nf[i]/nc[i] (i < B),
    // mask lanes >= b, butterfly-reduce. All 4 waves compute redundantly.
    int nfv = 0, ncv = 0;
    if (lane < B) { nfv = nf[lane]; ncv = nc[lane]; }
    const int nf_b = __shfl(nfv, b);
    const int nc_b = __shfl(ncv, b);
    int fo = (lane < b) ? nfv : 0;
    int co = (lane < b) ? ncv : 0;
    #pragma unroll
    for (int off = 32; off > 0; off >>= 1) {
        fo += __shfl_xor(fo, off);
        co += __shfl_xor(co, off);
    }
    // fo = foff[b], co = coff[b], wave-uniform.

    if (j == 0 && t == 0) src_len[b] = (float)nf_b;  // harness reads f32

    f32x4* out4 = (f32x4*)(out + (size_t)(b * L + j) * D_TOT);

    if (j >= nf_b) {
        const float pv = (float)(*pad_idx_p);
        const f32x4 p4 = {pv, pv, pv, pv};
        __builtin_nontemporal_store(p4, &out4[t]);
        __builtin_nontemporal_store(p4, &out4[256 + t]);
        return;
    }

    const int rf = nf_b / nc_b;             // repeat factor (==4 here, general)
    int cidx = j / rf;
    const int last = nc_b - 1;
    if (cidx > last) cidx = last;           // remainder tail clamps to last clip

    const f32x4* img4 = (const f32x4*)(image + (size_t)(fo + j) * D_IMG);
    const f32x4* clp4 = (const f32x4*)(clip  + (size_t)(co + cidx) * D_IMG);

    // image: read-once stream -> NT load; clip: 4x reuse (same XCD now) -> cached.
    f32x4 iv = __builtin_nontemporal_load(&img4[t]);
    f32x4 cv = clp4[t];
    __builtin_nontemporal_store(iv, &out4[t]);          // elements [0,1024)
    __builtin_nontemporal_store(cv, &out4[256 + t]);    // elements [1024,2048)
}

extern "C" void kernel_launch(void* const* d_in, const int* in_sizes, int n_in,
                              void* d_out, int out_size, void* d_ws, size_t ws_size,
                              hipStream_t stream) {
    const float* image = (const float*)d_in[0];
    // d_in[1] (emo_batch) is unused by the reference.
    const float* clip  = (const float*)d_in[2];
    const int*   nf    = (const int*)d_in[3];
    const int*   nc    = (const int*)d_in[4];
    const int*   pad   = (const int*)d_in[5];

    const int B = in_sizes[3];
    const int L = (out_size - B) / (B * D_TOT);

    float* out = (float*)d_out;
    float* src_len = (float*)d_out + (size_t)B * L * D_TOT;  // tail: src_length [B]

    const int nwg = B * L;
    const int chunk = (nwg % NXCD == 0) ? nwg / NXCD : 0;  // 0 -> identity map

    gather_kernel<<<nwg, 256, 0, stream>>>(image, clip, nf, nc, pad, out, src_len,
                                           L, B, chunk);
}